// Round 1
// baseline (6375.094 us; speedup 1.0000x reference)
//
#include <hip/hip_runtime.h>

#define NA   100000
#define NP   1600000
#define FDIM 128
#define NRBF 32
#define LN2  0.69314718055994530942f

// ShiftedSoftplus, overflow-stable: softplus(x) - ln2
__device__ __forceinline__ float ssp_f(float v) {
    return fmaxf(v, 0.0f) + log1pf(__expf(-fabsf(v))) - LN2;
}

// ---------------------------------------------------------------------------
// K1: h = x @ W_in   (no bias). 32 atoms per 256-thread block.
// Thread t computes rows {r0, r0+1} x cols [c0, c0+8), r0=(t>>4)*2, c0=(t&15)*8
// ---------------------------------------------------------------------------
__global__ __launch_bounds__(256) void k_in_proj(const float* __restrict__ x,
                                                 const float* __restrict__ W,
                                                 float* __restrict__ h) {
    __shared__ float Xs[32 * 132];   // stride 132: 16B-aligned rows, bank-shift 4/row
    const int t  = threadIdx.x;
    const int r0g = blockIdx.x * 32;

    // load 32x128 fp32 tile = 1024 float4
    const float4* xv = (const float4*)(x + (size_t)r0g * FDIM);
    #pragma unroll
    for (int i = 0; i < 4; ++i) {
        int idx = t + i * 256;
        int row = idx >> 5;         // 32 float4 per row
        int c4  = idx & 31;
        *(float4*)(&Xs[row * 132 + c4 * 4]) = xv[idx];
    }
    __syncthreads();

    const int c0 = (t & 15) * 8;
    const int r0 = (t >> 4) * 2;
    float acc[2][8] = {};
    #pragma unroll 4
    for (int k = 0; k < FDIM; ++k) {
        float xa = Xs[r0 * 132 + k];
        float xb = Xs[(r0 + 1) * 132 + k];
        float4 w0 = *(const float4*)(W + k * FDIM + c0);
        float4 w1 = *(const float4*)(W + k * FDIM + c0 + 4);
        float wv[8] = {w0.x, w0.y, w0.z, w0.w, w1.x, w1.y, w1.z, w1.w};
        #pragma unroll
        for (int j = 0; j < 8; ++j) {
            acc[0][j] += xa * wv[j];
            acc[1][j] += xb * wv[j];
        }
    }
    #pragma unroll
    for (int i = 0; i < 2; ++i) {
        float4 o0 = {acc[i][0], acc[i][1], acc[i][2], acc[i][3]};
        float4 o1 = {acc[i][4], acc[i][5], acc[i][6], acc[i][7]};
        float* hp = h + (size_t)(r0g + r0 + i) * FDIM + c0;
        *(float4*)(hp)     = o0;
        *(float4*)(hp + 4) = o1;
    }
}

// ---------------------------------------------------------------------------
// K2: fused filter network + gather + scatter. 64 pairs per 256-thread block.
//   tmp  = ssp(F @ Wf1 + bf1)            [64 x 128]
//   Wij  = (tmp @ Wf2 + bf2) * cutoff    [64 x 128]
//   atomicAdd(acc[idx_i], h[idx_j] * Wij)
// Thread t: rows {r0..r0+3} x cols [c0, c0+8), r0=(t>>4)*4, c0=(t&15)*8
// ---------------------------------------------------------------------------
__global__ __launch_bounds__(256) void k_pairs(const int*   __restrict__ pl,
                                               const float* __restrict__ fij,
                                               const float* __restrict__ fcut,
                                               const float* __restrict__ h,
                                               const float* __restrict__ Wf1,
                                               const float* __restrict__ bf1,
                                               const float* __restrict__ Wf2,
                                               const float* __restrict__ bf2,
                                               float* __restrict__ acc_out) {
    __shared__ float Fs[64 * 36];     // 64 x 32, stride 36
    __shared__ float Tmp[64 * 132];   // 64 x 128, stride 132
    __shared__ int   pis[64], pjs[64];
    __shared__ float cuts[64];

    const int t  = threadIdx.x;
    const int p0 = blockIdx.x * 64;

    // load F tile: 64*32 floats = 512 float4
    const float4* fv = (const float4*)(fij + (size_t)p0 * NRBF);
    #pragma unroll
    for (int i = 0; i < 2; ++i) {
        int idx = t + i * 256;
        int row = idx >> 3;          // 8 float4 per row
        int c4  = idx & 7;
        *(float4*)(&Fs[row * 36 + c4 * 4]) = fv[idx];
    }
    if (t < 64) {
        pis[t]  = pl[p0 + t];
        pjs[t]  = pl[NP + p0 + t];
        cuts[t] = fcut[p0 + t];
    }
    __syncthreads();

    const int c0 = (t & 15) * 8;
    const int r0 = (t >> 4) * 4;

    // ---- phase 1: tmp = ssp(F @ Wf1 + bf1) ----
    float a1[4][8] = {};
    #pragma unroll 4
    for (int k = 0; k < NRBF; ++k) {
        float4 w0 = *(const float4*)(Wf1 + k * FDIM + c0);
        float4 w1 = *(const float4*)(Wf1 + k * FDIM + c0 + 4);
        float wv[8] = {w0.x, w0.y, w0.z, w0.w, w1.x, w1.y, w1.z, w1.w};
        float xr[4];
        #pragma unroll
        for (int i = 0; i < 4; ++i) xr[i] = Fs[(r0 + i) * 36 + k];
        #pragma unroll
        for (int i = 0; i < 4; ++i)
            #pragma unroll
            for (int j = 0; j < 8; ++j)
                a1[i][j] += xr[i] * wv[j];
    }
    {
        float4 b0 = *(const float4*)(bf1 + c0);
        float4 b1 = *(const float4*)(bf1 + c0 + 4);
        float bv[8] = {b0.x, b0.y, b0.z, b0.w, b1.x, b1.y, b1.z, b1.w};
        #pragma unroll
        for (int i = 0; i < 4; ++i)
            #pragma unroll
            for (int j = 0; j < 8; ++j)
                Tmp[(r0 + i) * 132 + c0 + j] = ssp_f(a1[i][j] + bv[j]);
    }
    __syncthreads();

    // ---- phase 2: Wij = tmp @ Wf2 + bf2 ----
    float a2[4][8] = {};
    #pragma unroll 2
    for (int k = 0; k < FDIM; ++k) {
        float4 w0 = *(const float4*)(Wf2 + k * FDIM + c0);
        float4 w1 = *(const float4*)(Wf2 + k * FDIM + c0 + 4);
        float wv[8] = {w0.x, w0.y, w0.z, w0.w, w1.x, w1.y, w1.z, w1.w};
        float xr[4];
        #pragma unroll
        for (int i = 0; i < 4; ++i) xr[i] = Tmp[(r0 + i) * 132 + k];
        #pragma unroll
        for (int i = 0; i < 4; ++i)
            #pragma unroll
            for (int j = 0; j < 8; ++j)
                a2[i][j] += xr[i] * wv[j];
    }

    // ---- phase 3: cutoff * Wij * h[idx_j], scatter to acc_out[idx_i] ----
    float4 b20 = *(const float4*)(bf2 + c0);
    float4 b21 = *(const float4*)(bf2 + c0 + 4);
    float bv[8] = {b20.x, b20.y, b20.z, b20.w, b21.x, b21.y, b21.z, b21.w};
    #pragma unroll
    for (int i = 0; i < 4; ++i) {
        int   p   = r0 + i;
        float cut = cuts[p];
        int   aj  = pjs[p];
        int   ai  = pis[p];
        const float* hr = h + (size_t)aj * FDIM + c0;
        float4 h0 = *(const float4*)(hr);
        float4 h1 = *(const float4*)(hr + 4);
        float hv[8] = {h0.x, h0.y, h0.z, h0.w, h1.x, h1.y, h1.z, h1.w};
        float* outp = acc_out + (size_t)ai * FDIM + c0;
        #pragma unroll
        for (int j = 0; j < 8; ++j) {
            float v = (a2[i][j] + bv[j]) * cut * hv[j];
            unsafeAtomicAdd(outp + j, v);   // native global_atomic_add_f32
        }
    }
}

// ---------------------------------------------------------------------------
// K3: out = ssp(acc @ Wo1 + bo1) @ Wo2 + bo2. 32 atoms per 256-thread block.
// ---------------------------------------------------------------------------
__global__ __launch_bounds__(256) void k_out(const float* __restrict__ acc_in,
                                             const float* __restrict__ Wo1,
                                             const float* __restrict__ bo1,
                                             const float* __restrict__ Wo2,
                                             const float* __restrict__ bo2,
                                             float* __restrict__ out) {
    __shared__ float As[32 * 132];
    __shared__ float O1[32 * 132];
    const int t   = threadIdx.x;
    const int r0g = blockIdx.x * 32;

    const float4* av = (const float4*)(acc_in + (size_t)r0g * FDIM);
    #pragma unroll
    for (int i = 0; i < 4; ++i) {
        int idx = t + i * 256;
        int row = idx >> 5;
        int c4  = idx & 31;
        *(float4*)(&As[row * 132 + c4 * 4]) = av[idx];
    }
    __syncthreads();

    const int c0 = (t & 15) * 8;
    const int r0 = (t >> 4) * 2;

    // phase A: O1 = ssp(acc @ Wo1 + bo1)
    float acc[2][8] = {};
    #pragma unroll 4
    for (int k = 0; k < FDIM; ++k) {
        float xa = As[r0 * 132 + k];
        float xb = As[(r0 + 1) * 132 + k];
        float4 w0 = *(const float4*)(Wo1 + k * FDIM + c0);
        float4 w1 = *(const float4*)(Wo1 + k * FDIM + c0 + 4);
        float wv[8] = {w0.x, w0.y, w0.z, w0.w, w1.x, w1.y, w1.z, w1.w};
        #pragma unroll
        for (int j = 0; j < 8; ++j) {
            acc[0][j] += xa * wv[j];
            acc[1][j] += xb * wv[j];
        }
    }
    {
        float4 b0 = *(const float4*)(bo1 + c0);
        float4 b1 = *(const float4*)(bo1 + c0 + 4);
        float bv[8] = {b0.x, b0.y, b0.z, b0.w, b1.x, b1.y, b1.z, b1.w};
        #pragma unroll
        for (int i = 0; i < 2; ++i)
            #pragma unroll
            for (int j = 0; j < 8; ++j)
                O1[(r0 + i) * 132 + c0 + j] = ssp_f(acc[i][j] + bv[j]);
    }
    __syncthreads();

    // phase B: out = O1 @ Wo2 + bo2
    float acc2[2][8] = {};
    #pragma unroll 4
    for (int k = 0; k < FDIM; ++k) {
        float xa = O1[r0 * 132 + k];
        float xb = O1[(r0 + 1) * 132 + k];
        float4 w0 = *(const float4*)(Wo2 + k * FDIM + c0);
        float4 w1 = *(const float4*)(Wo2 + k * FDIM + c0 + 4);
        float wv[8] = {w0.x, w0.y, w0.z, w0.w, w1.x, w1.y, w1.z, w1.w};
        #pragma unroll
        for (int j = 0; j < 8; ++j) {
            acc2[0][j] += xa * wv[j];
            acc2[1][j] += xb * wv[j];
        }
    }
    float4 b0 = *(const float4*)(bo2 + c0);
    float4 b1 = *(const float4*)(bo2 + c0 + 4);
    float bv[8] = {b0.x, b0.y, b0.z, b0.w, b1.x, b1.y, b1.z, b1.w};
    #pragma unroll
    for (int i = 0; i < 2; ++i) {
        float4 o0 = {acc2[i][0] + bv[0], acc2[i][1] + bv[1],
                     acc2[i][2] + bv[2], acc2[i][3] + bv[3]};
        float4 o1 = {acc2[i][4] + bv[4], acc2[i][5] + bv[5],
                     acc2[i][6] + bv[6], acc2[i][7] + bv[7]};
        float* op = out + (size_t)(r0g + r0 + i) * FDIM + c0;
        *(float4*)(op)     = o0;
        *(float4*)(op + 4) = o1;
    }
}

extern "C" void kernel_launch(void* const* d_in, const int* in_sizes, int n_in,
                              void* d_out, int out_size, void* d_ws, size_t ws_size,
                              hipStream_t stream) {
    const float* x    = (const float*)d_in[0];
    const int*   pl   = (const int*)  d_in[1];
    const float* fij  = (const float*)d_in[2];
    const float* fcut = (const float*)d_in[3];
    const float* W_in = (const float*)d_in[4];
    const float* Wf1  = (const float*)d_in[5];
    const float* bf1  = (const float*)d_in[6];
    const float* Wf2  = (const float*)d_in[7];
    const float* bf2  = (const float*)d_in[8];
    const float* Wo1  = (const float*)d_in[9];
    const float* bo1  = (const float*)d_in[10];
    const float* Wo2  = (const float*)d_in[11];
    const float* bo2  = (const float*)d_in[12];
    float* out = (float*)d_out;

    float* h   = (float*)d_ws;                       // [NA, 128] fp32
    float* acc = h + (size_t)NA * FDIM;              // [NA, 128] fp32

    // acc must be zero every call (ws re-poisoned to 0xAA)
    hipMemsetAsync(acc, 0, (size_t)NA * FDIM * sizeof(float), stream);

    k_in_proj<<<NA / 32, 256, 0, stream>>>(x, W_in, h);
    k_pairs  <<<NP / 64, 256, 0, stream>>>(pl, fij, fcut, h, Wf1, bf1, Wf2, bf2, acc);
    k_out    <<<NA / 32, 256, 0, stream>>>(acc, Wo1, bo1, Wo2, bo2, out);
}

// Round 2
// 2353.930 us; speedup vs baseline: 2.7083x; 2.7083x over previous
//
#include <hip/hip_runtime.h>

#define NA   100000
#define NP   1600000
#define FDIM 128
#define NRBF 32
#define LN2  0.69314718055994530942f

// ShiftedSoftplus, overflow-stable: softplus(x) - ln2
__device__ __forceinline__ float ssp_f(float v) {
    return fmaxf(v, 0.0f) + log1pf(__expf(-fabsf(v))) - LN2;
}

// ---------------------------------------------------------------------------
// K1: h = x @ W_in   (no bias). 32 atoms per 256-thread block.
// ---------------------------------------------------------------------------
__global__ __launch_bounds__(256) void k_in_proj(const float* __restrict__ x,
                                                 const float* __restrict__ W,
                                                 float* __restrict__ h) {
    __shared__ float Xs[32 * 132];
    const int t  = threadIdx.x;
    const int r0g = blockIdx.x * 32;

    const float4* xv = (const float4*)(x + (size_t)r0g * FDIM);
    #pragma unroll
    for (int i = 0; i < 4; ++i) {
        int idx = t + i * 256;
        int row = idx >> 5;
        int c4  = idx & 31;
        *(float4*)(&Xs[row * 132 + c4 * 4]) = xv[idx];
    }
    __syncthreads();

    const int c0 = (t & 15) * 8;
    const int r0 = (t >> 4) * 2;
    float acc[2][8] = {};
    #pragma unroll 4
    for (int k = 0; k < FDIM; ++k) {
        float xa = Xs[r0 * 132 + k];
        float xb = Xs[(r0 + 1) * 132 + k];
        float4 w0 = *(const float4*)(W + k * FDIM + c0);
        float4 w1 = *(const float4*)(W + k * FDIM + c0 + 4);
        float wv[8] = {w0.x, w0.y, w0.z, w0.w, w1.x, w1.y, w1.z, w1.w};
        #pragma unroll
        for (int j = 0; j < 8; ++j) {
            acc[0][j] += xa * wv[j];
            acc[1][j] += xb * wv[j];
        }
    }
    #pragma unroll
    for (int i = 0; i < 2; ++i) {
        float4 o0 = {acc[i][0], acc[i][1], acc[i][2], acc[i][3]};
        float4 o1 = {acc[i][4], acc[i][5], acc[i][6], acc[i][7]};
        float* hp = h + (size_t)(r0g + r0 + i) * FDIM + c0;
        *(float4*)(hp)     = o0;
        *(float4*)(hp + 4) = o1;
    }
}

// ---------------------------------------------------------------------------
// Sort pipeline: counting sort of pairs by idx_i.
// ---------------------------------------------------------------------------
__global__ void k_hist(const int* __restrict__ pl, int* __restrict__ count) {
    int p = blockIdx.x * 256 + threadIdx.x;
    if (p < NP) atomicAdd(&count[pl[p]], 1);
}

__global__ __launch_bounds__(256) void k_scan1(const int* __restrict__ count,
                                               int* __restrict__ base,
                                               int* __restrict__ bsum) {
    __shared__ int sh[256];
    int i = blockIdx.x * 256 + threadIdx.x;
    int v = (i < NA) ? count[i] : 0;
    sh[threadIdx.x] = v;
    __syncthreads();
    for (int off = 1; off < 256; off <<= 1) {
        int add = (threadIdx.x >= off) ? sh[threadIdx.x - off] : 0;
        __syncthreads();
        sh[threadIdx.x] += add;
        __syncthreads();
    }
    if (i < NA) base[i] = sh[threadIdx.x] - v;     // exclusive
    if (threadIdx.x == 255) bsum[blockIdx.x] = sh[255];
}

__global__ void k_scan2(int* __restrict__ bsum, int nb) {
    if (threadIdx.x == 0 && blockIdx.x == 0) {
        int run = 0;
        for (int i = 0; i < nb; ++i) { int v = bsum[i]; bsum[i] = run; run += v; }
    }
}

__global__ void k_scan3(const int* __restrict__ bsum, int* __restrict__ base,
                        int* __restrict__ cursor) {
    int i = blockIdx.x * 256 + threadIdx.x;
    if (i < NA) {
        int b = base[i] + bsum[blockIdx.x];
        base[i]   = b;
        cursor[i] = b;
    }
}

__global__ void k_reorder(const int* __restrict__ pl, int* __restrict__ cursor,
                          int* __restrict__ perm) {
    int p = blockIdx.x * 256 + threadIdx.x;
    if (p < NP) {
        int pos = atomicAdd(&cursor[pl[p]], 1);
        perm[pos] = p;
    }
}

// ---------------------------------------------------------------------------
// K2-sorted: fused filter network + gather + LDS-aggregated scatter.
// 64 *sorted* pairs per block; pairs sharing idx_i are adjacent, so the block
// touches ~5 distinct atoms. Accumulate per-slot rows in LDS (ds_add_f32),
// flush one global-atomic row per slot: ~12x fewer global atomics.
// ---------------------------------------------------------------------------
__global__ __launch_bounds__(256) void k_pairs_sorted(
        const int*   __restrict__ perm,
        const int*   __restrict__ pl,
        const float* __restrict__ fij,
        const float* __restrict__ fcut,
        const float* __restrict__ h,
        const float* __restrict__ Wf1,
        const float* __restrict__ bf1,
        const float* __restrict__ Wf2,
        const float* __restrict__ bf2,
        float* __restrict__ acc_out) {
    __shared__ float Fs[64 * 36];
    __shared__ float Tmp[64 * 132];   // phase-2 activations, then slot accumulators
    __shared__ int   ajs[64], sps[64], slots[64], slot_atom[64];
    __shared__ float cuts[64];
    __shared__ int   nslots_s;

    const int t  = threadIdx.x;
    const int p0 = blockIdx.x * 64;

    if (t < 64) {   // exactly wave 0 (wavefront = 64)
        int sp = perm[p0 + t];
        int ai = pl[sp];
        sps[t]  = sp;
        ajs[t]  = pl[NP + sp];
        cuts[t] = fcut[sp];
        int prev = __shfl_up(ai, 1);
        bool head = (t == 0) || (ai != prev);
        unsigned long long mask = __ballot(head);
        int slot = __popcll(mask & ((2ULL << t) - 1)) - 1;
        slots[t] = slot;
        if (head) slot_atom[slot] = ai;
        if (t == 0) nslots_s = (int)__popcll(mask);
    }
    __syncthreads();

    // gather F tile rows via perm (128 B/row, 2 cachelines, contiguous per row)
    #pragma unroll
    for (int i = 0; i < 2; ++i) {
        int idx = t + i * 256;
        int row = idx >> 3;
        int c4  = idx & 7;
        const float4* fv = (const float4*)(fij + (size_t)sps[row] * NRBF);
        *(float4*)(&Fs[row * 36 + c4 * 4]) = fv[c4];
    }
    __syncthreads();

    const int c0 = (t & 15) * 8;
    const int r0 = (t >> 4) * 4;

    // ---- phase 1: tmp = ssp(F @ Wf1 + bf1) ----
    float a1[4][8] = {};
    #pragma unroll 4
    for (int k = 0; k < NRBF; ++k) {
        float4 w0 = *(const float4*)(Wf1 + k * FDIM + c0);
        float4 w1 = *(const float4*)(Wf1 + k * FDIM + c0 + 4);
        float wv[8] = {w0.x, w0.y, w0.z, w0.w, w1.x, w1.y, w1.z, w1.w};
        float xr[4];
        #pragma unroll
        for (int i = 0; i < 4; ++i) xr[i] = Fs[(r0 + i) * 36 + k];
        #pragma unroll
        for (int i = 0; i < 4; ++i)
            #pragma unroll
            for (int j = 0; j < 8; ++j)
                a1[i][j] += xr[i] * wv[j];
    }
    {
        float4 b0 = *(const float4*)(bf1 + c0);
        float4 b1 = *(const float4*)(bf1 + c0 + 4);
        float bv[8] = {b0.x, b0.y, b0.z, b0.w, b1.x, b1.y, b1.z, b1.w};
        #pragma unroll
        for (int i = 0; i < 4; ++i)
            #pragma unroll
            for (int j = 0; j < 8; ++j)
                Tmp[(r0 + i) * 132 + c0 + j] = ssp_f(a1[i][j] + bv[j]);
    }
    __syncthreads();

    // ---- phase 2: Wij = tmp @ Wf2 + bf2 (kept in regs) ----
    float a2[4][8] = {};
    #pragma unroll 2
    for (int k = 0; k < FDIM; ++k) {
        float4 w0 = *(const float4*)(Wf2 + k * FDIM + c0);
        float4 w1 = *(const float4*)(Wf2 + k * FDIM + c0 + 4);
        float wv[8] = {w0.x, w0.y, w0.z, w0.w, w1.x, w1.y, w1.z, w1.w};
        float xr[4];
        #pragma unroll
        for (int i = 0; i < 4; ++i) xr[i] = Tmp[(r0 + i) * 132 + k];
        #pragma unroll
        for (int i = 0; i < 4; ++i)
            #pragma unroll
            for (int j = 0; j < 8; ++j)
                a2[i][j] += xr[i] * wv[j];
    }
    __syncthreads();   // all reads of Tmp done; reuse as slot accumulator

    // zero slot accumulator patches (covers rows 0..63 x cols 0..127)
    #pragma unroll
    for (int i = 0; i < 4; ++i)
        #pragma unroll
        for (int j = 0; j < 8; ++j)
            Tmp[(r0 + i) * 132 + c0 + j] = 0.f;
    __syncthreads();

    // ---- phase 3: v = (Wij+b)*cut*h[idx_j]; run-combine per slot -> LDS ----
    {
        float4 b20 = *(const float4*)(bf2 + c0);
        float4 b21 = *(const float4*)(bf2 + c0 + 4);
        float bv[8] = {b20.x, b20.y, b20.z, b20.w, b21.x, b21.y, b21.z, b21.w};
        float run[8] = {};
        int cur = slots[r0];
        #pragma unroll
        for (int i = 0; i < 4; ++i) {
            int p = r0 + i;
            int s = slots[p];
            if (s != cur) {
                #pragma unroll
                for (int j = 0; j < 8; ++j) {
                    atomicAdd(&Tmp[cur * 132 + c0 + j], run[j]);
                    run[j] = 0.f;
                }
                cur = s;
            }
            float cut = cuts[p];
            const float* hr = h + (size_t)ajs[p] * FDIM + c0;
            float4 h0 = *(const float4*)(hr);
            float4 h1 = *(const float4*)(hr + 4);
            float hv[8] = {h0.x, h0.y, h0.z, h0.w, h1.x, h1.y, h1.z, h1.w};
            #pragma unroll
            for (int j = 0; j < 8; ++j)
                run[j] += (a2[i][j] + bv[j]) * cut * hv[j];
        }
        #pragma unroll
        for (int j = 0; j < 8; ++j)
            atomicAdd(&Tmp[cur * 132 + c0 + j], run[j]);
    }
    __syncthreads();

    // ---- flush: one global-atomic row per distinct atom in this block ----
    int nslots = nslots_s;
    for (int s = (t >> 4); s < nslots; s += 16) {
        float* outp = acc_out + (size_t)slot_atom[s] * FDIM + c0;
        #pragma unroll
        for (int j = 0; j < 8; ++j)
            unsafeAtomicAdd(outp + j, Tmp[s * 132 + c0 + j]);
    }
}

// ---------------------------------------------------------------------------
// K2-unsorted fallback (round-1 version) if ws is too small for sort buffers.
// ---------------------------------------------------------------------------
__global__ __launch_bounds__(256) void k_pairs(const int*   __restrict__ pl,
                                               const float* __restrict__ fij,
                                               const float* __restrict__ fcut,
                                               const float* __restrict__ h,
                                               const float* __restrict__ Wf1,
                                               const float* __restrict__ bf1,
                                               const float* __restrict__ Wf2,
                                               const float* __restrict__ bf2,
                                               float* __restrict__ acc_out) {
    __shared__ float Fs[64 * 36];
    __shared__ float Tmp[64 * 132];
    __shared__ int   pis[64], pjs[64];
    __shared__ float cuts[64];

    const int t  = threadIdx.x;
    const int p0 = blockIdx.x * 64;

    const float4* fv = (const float4*)(fij + (size_t)p0 * NRBF);
    #pragma unroll
    for (int i = 0; i < 2; ++i) {
        int idx = t + i * 256;
        int row = idx >> 3;
        int c4  = idx & 7;
        *(float4*)(&Fs[row * 36 + c4 * 4]) = fv[idx];
    }
    if (t < 64) {
        pis[t]  = pl[p0 + t];
        pjs[t]  = pl[NP + p0 + t];
        cuts[t] = fcut[p0 + t];
    }
    __syncthreads();

    const int c0 = (t & 15) * 8;
    const int r0 = (t >> 4) * 4;

    float a1[4][8] = {};
    #pragma unroll 4
    for (int k = 0; k < NRBF; ++k) {
        float4 w0 = *(const float4*)(Wf1 + k * FDIM + c0);
        float4 w1 = *(const float4*)(Wf1 + k * FDIM + c0 + 4);
        float wv[8] = {w0.x, w0.y, w0.z, w0.w, w1.x, w1.y, w1.z, w1.w};
        float xr[4];
        #pragma unroll
        for (int i = 0; i < 4; ++i) xr[i] = Fs[(r0 + i) * 36 + k];
        #pragma unroll
        for (int i = 0; i < 4; ++i)
            #pragma unroll
            for (int j = 0; j < 8; ++j)
                a1[i][j] += xr[i] * wv[j];
    }
    {
        float4 b0 = *(const float4*)(bf1 + c0);
        float4 b1 = *(const float4*)(bf1 + c0 + 4);
        float bv[8] = {b0.x, b0.y, b0.z, b0.w, b1.x, b1.y, b1.z, b1.w};
        #pragma unroll
        for (int i = 0; i < 4; ++i)
            #pragma unroll
            for (int j = 0; j < 8; ++j)
                Tmp[(r0 + i) * 132 + c0 + j] = ssp_f(a1[i][j] + bv[j]);
    }
    __syncthreads();

    float a2[4][8] = {};
    #pragma unroll 2
    for (int k = 0; k < FDIM; ++k) {
        float4 w0 = *(const float4*)(Wf2 + k * FDIM + c0);
        float4 w1 = *(const float4*)(Wf2 + k * FDIM + c0 + 4);
        float wv[8] = {w0.x, w0.y, w0.z, w0.w, w1.x, w1.y, w1.z, w1.w};
        float xr[4];
        #pragma unroll
        for (int i = 0; i < 4; ++i) xr[i] = Tmp[(r0 + i) * 132 + k];
        #pragma unroll
        for (int i = 0; i < 4; ++i)
            #pragma unroll
            for (int j = 0; j < 8; ++j)
                a2[i][j] += xr[i] * wv[j];
    }

    float4 b20 = *(const float4*)(bf2 + c0);
    float4 b21 = *(const float4*)(bf2 + c0 + 4);
    float bv[8] = {b20.x, b20.y, b20.z, b20.w, b21.x, b21.y, b21.z, b21.w};
    #pragma unroll
    for (int i = 0; i < 4; ++i) {
        int   p   = r0 + i;
        float cut = cuts[p];
        const float* hr = h + (size_t)pjs[p] * FDIM + c0;
        float4 h0 = *(const float4*)(hr);
        float4 h1 = *(const float4*)(hr + 4);
        float hv[8] = {h0.x, h0.y, h0.z, h0.w, h1.x, h1.y, h1.z, h1.w};
        float* outp = acc_out + (size_t)pis[p] * FDIM + c0;
        #pragma unroll
        for (int j = 0; j < 8; ++j)
            unsafeAtomicAdd(outp + j, (a2[i][j] + bv[j]) * cut * hv[j]);
    }
}

// ---------------------------------------------------------------------------
// K3: out = ssp(acc @ Wo1 + bo1) @ Wo2 + bo2. 32 atoms per 256-thread block.
// ---------------------------------------------------------------------------
__global__ __launch_bounds__(256) void k_out(const float* __restrict__ acc_in,
                                             const float* __restrict__ Wo1,
                                             const float* __restrict__ bo1,
                                             const float* __restrict__ Wo2,
                                             const float* __restrict__ bo2,
                                             float* __restrict__ out) {
    __shared__ float As[32 * 132];
    __shared__ float O1[32 * 132];
    const int t   = threadIdx.x;
    const int r0g = blockIdx.x * 32;

    const float4* av = (const float4*)(acc_in + (size_t)r0g * FDIM);
    #pragma unroll
    for (int i = 0; i < 4; ++i) {
        int idx = t + i * 256;
        int row = idx >> 5;
        int c4  = idx & 31;
        *(float4*)(&As[row * 132 + c4 * 4]) = av[idx];
    }
    __syncthreads();

    const int c0 = (t & 15) * 8;
    const int r0 = (t >> 4) * 2;

    float acc[2][8] = {};
    #pragma unroll 4
    for (int k = 0; k < FDIM; ++k) {
        float xa = As[r0 * 132 + k];
        float xb = As[(r0 + 1) * 132 + k];
        float4 w0 = *(const float4*)(Wo1 + k * FDIM + c0);
        float4 w1 = *(const float4*)(Wo1 + k * FDIM + c0 + 4);
        float wv[8] = {w0.x, w0.y, w0.z, w0.w, w1.x, w1.y, w1.z, w1.w};
        #pragma unroll
        for (int j = 0; j < 8; ++j) {
            acc[0][j] += xa * wv[j];
            acc[1][j] += xb * wv[j];
        }
    }
    {
        float4 b0 = *(const float4*)(bo1 + c0);
        float4 b1 = *(const float4*)(bo1 + c0 + 4);
        float bv[8] = {b0.x, b0.y, b0.z, b0.w, b1.x, b1.y, b1.z, b1.w};
        #pragma unroll
        for (int i = 0; i < 2; ++i)
            #pragma unroll
            for (int j = 0; j < 8; ++j)
                O1[(r0 + i) * 132 + c0 + j] = ssp_f(acc[i][j] + bv[j]);
    }
    __syncthreads();

    float acc2[2][8] = {};
    #pragma unroll 4
    for (int k = 0; k < FDIM; ++k) {
        float xa = O1[r0 * 132 + k];
        float xb = O1[(r0 + 1) * 132 + k];
        float4 w0 = *(const float4*)(Wo2 + k * FDIM + c0);
        float4 w1 = *(const float4*)(Wo2 + k * FDIM + c0 + 4);
        float wv[8] = {w0.x, w0.y, w0.z, w0.w, w1.x, w1.y, w1.z, w1.w};
        #pragma unroll
        for (int j = 0; j < 8; ++j) {
            acc2[0][j] += xa * wv[j];
            acc2[1][j] += xb * wv[j];
        }
    }
    float4 b0 = *(const float4*)(bo2 + c0);
    float4 b1 = *(const float4*)(bo2 + c0 + 4);
    float bv[8] = {b0.x, b0.y, b0.z, b0.w, b1.x, b1.y, b1.z, b1.w};
    #pragma unroll
    for (int i = 0; i < 2; ++i) {
        float4 o0 = {acc2[i][0] + bv[0], acc2[i][1] + bv[1],
                     acc2[i][2] + bv[2], acc2[i][3] + bv[3]};
        float4 o1 = {acc2[i][4] + bv[4], acc2[i][5] + bv[5],
                     acc2[i][6] + bv[6], acc2[i][7] + bv[7]};
        float* op = out + (size_t)(r0g + r0 + i) * FDIM + c0;
        *(float4*)(op)     = o0;
        *(float4*)(op + 4) = o1;
    }
}

extern "C" void kernel_launch(void* const* d_in, const int* in_sizes, int n_in,
                              void* d_out, int out_size, void* d_ws, size_t ws_size,
                              hipStream_t stream) {
    const float* x    = (const float*)d_in[0];
    const int*   pl   = (const int*)  d_in[1];
    const float* fij  = (const float*)d_in[2];
    const float* fcut = (const float*)d_in[3];
    const float* W_in = (const float*)d_in[4];
    const float* Wf1  = (const float*)d_in[5];
    const float* bf1  = (const float*)d_in[6];
    const float* Wf2  = (const float*)d_in[7];
    const float* bf2  = (const float*)d_in[8];
    const float* Wo1  = (const float*)d_in[9];
    const float* bo1  = (const float*)d_in[10];
    const float* Wo2  = (const float*)d_in[11];
    const float* bo2  = (const float*)d_in[12];
    float* out = (float*)d_out;

    // ws layout
    char*  wsp   = (char*)d_ws;
    float* h     = (float*)wsp;                              // NA*128 f32
    float* acc   = h + (size_t)NA * FDIM;                    // NA*128 f32
    int*   count = (int*)(acc + (size_t)NA * FDIM);          // NA int
    int*   base  = count + NA;                               // NA int
    int*   cursor= base + NA;                                // NA int
    int*   bsum  = cursor + NA;                              // 512 int
    int*   perm  = bsum + 512;                               // NP int

    const size_t needed = (size_t)NA * FDIM * 2 * 4
                        + ((size_t)NA * 3 + 512 + NP) * 4;
    const bool sorted_path = (ws_size >= needed);

    const int NB = (NA + 255) / 256;   // 391 scan blocks

    hipMemsetAsync(acc, 0, (size_t)NA * FDIM * sizeof(float), stream);
    k_in_proj<<<NA / 32, 256, 0, stream>>>(x, W_in, h);

    if (sorted_path) {
        hipMemsetAsync(count, 0, (size_t)NA * sizeof(int), stream);
        k_hist   <<<(NP + 255) / 256, 256, 0, stream>>>(pl, count);
        k_scan1  <<<NB, 256, 0, stream>>>(count, base, bsum);
        k_scan2  <<<1, 64, 0, stream>>>(bsum, NB);
        k_scan3  <<<NB, 256, 0, stream>>>(bsum, base, cursor);
        k_reorder<<<(NP + 255) / 256, 256, 0, stream>>>(pl, cursor, perm);
        k_pairs_sorted<<<NP / 64, 256, 0, stream>>>(perm, pl, fij, fcut, h,
                                                    Wf1, bf1, Wf2, bf2, acc);
    } else {
        k_pairs<<<NP / 64, 256, 0, stream>>>(pl, fij, fcut, h,
                                             Wf1, bf1, Wf2, bf2, acc);
    }

    k_out<<<NA / 32, 256, 0, stream>>>(acc, Wo1, bo1, Wo2, bo2, out);
}

// Round 3
// 1670.940 us; speedup vs baseline: 3.8153x; 1.4087x over previous
//
#include <hip/hip_runtime.h>

#define NA   100000
#define NP   1600000
#define FDIM 128
#define NRBF 32
#define LN2  0.69314718055994530942f

typedef __attribute__((ext_vector_type(8))) short short8;  // 8 bf16 = 4 VGPRs
typedef __attribute__((ext_vector_type(4))) float f32x4;

// ShiftedSoftplus, overflow-stable: softplus(x) - ln2
__device__ __forceinline__ float ssp_f(float v) {
    return fmaxf(v, 0.0f) + log1pf(__expf(-fabsf(v))) - LN2;
}

// f32 -> bf16 with round-to-nearest-even
__device__ __forceinline__ short f2bf(float f) {
    union { float f; unsigned u; } v; v.f = f;
    unsigned r = v.u + 0x7FFF + ((v.u >> 16) & 1);
    return (short)(r >> 16);
}

// ---------------------------------------------------------------------------
// K0: pre-transpose weights to bf16 in ws.
//   Wf1T[n*32  + k] = bf16(Wf1[k*128 + n])   n<128, k<32
//   Wf2T[n*128 + k] = bf16(Wf2[k*128 + n])   n<128, k<128
// ---------------------------------------------------------------------------
__global__ void k_prep(const float* __restrict__ Wf1, const float* __restrict__ Wf2,
                       short* __restrict__ Wf1T, short* __restrict__ Wf2T) {
    int i = blockIdx.x * 256 + threadIdx.x;          // grid covers 16384
    int n = i >> 7, k = i & 127;
    Wf2T[i] = f2bf(Wf2[k * FDIM + n]);
    if (i < 128 * 32) {
        int n1 = i >> 5, k1 = i & 31;
        Wf1T[i] = f2bf(Wf1[k1 * FDIM + n1]);
    }
}

// ---------------------------------------------------------------------------
// K1: h = x @ W_in   (no bias). 32 atoms per 256-thread block.
// ---------------------------------------------------------------------------
__global__ __launch_bounds__(256) void k_in_proj(const float* __restrict__ x,
                                                 const float* __restrict__ W,
                                                 float* __restrict__ h) {
    __shared__ float Xs[32 * 132];
    const int t  = threadIdx.x;
    const int r0g = blockIdx.x * 32;

    const float4* xv = (const float4*)(x + (size_t)r0g * FDIM);
    #pragma unroll
    for (int i = 0; i < 4; ++i) {
        int idx = t + i * 256;
        int row = idx >> 5;
        int c4  = idx & 31;
        *(float4*)(&Xs[row * 132 + c4 * 4]) = xv[idx];
    }
    __syncthreads();

    const int c0 = (t & 15) * 8;
    const int r0 = (t >> 4) * 2;
    float acc[2][8] = {};
    #pragma unroll 4
    for (int k = 0; k < FDIM; ++k) {
        float xa = Xs[r0 * 132 + k];
        float xb = Xs[(r0 + 1) * 132 + k];
        float4 w0 = *(const float4*)(W + k * FDIM + c0);
        float4 w1 = *(const float4*)(W + k * FDIM + c0 + 4);
        float wv[8] = {w0.x, w0.y, w0.z, w0.w, w1.x, w1.y, w1.z, w1.w};
        #pragma unroll
        for (int j = 0; j < 8; ++j) {
            acc[0][j] += xa * wv[j];
            acc[1][j] += xb * wv[j];
        }
    }
    #pragma unroll
    for (int i = 0; i < 2; ++i) {
        float4 o0 = {acc[i][0], acc[i][1], acc[i][2], acc[i][3]};
        float4 o1 = {acc[i][4], acc[i][5], acc[i][6], acc[i][7]};
        float* hp = h + (size_t)(r0g + r0 + i) * FDIM + c0;
        *(float4*)(hp)     = o0;
        *(float4*)(hp + 4) = o1;
    }
}

// ---------------------------------------------------------------------------
// Sort pipeline: counting sort of pairs by idx_i.
// ---------------------------------------------------------------------------
__global__ void k_hist(const int* __restrict__ pl, int* __restrict__ count) {
    int p = blockIdx.x * 256 + threadIdx.x;
    if (p < NP) atomicAdd(&count[pl[p]], 1);
}

__global__ __launch_bounds__(256) void k_scan1(const int* __restrict__ count,
                                               int* __restrict__ base,
                                               int* __restrict__ bsum) {
    __shared__ int sh[256];
    int i = blockIdx.x * 256 + threadIdx.x;
    int v = (i < NA) ? count[i] : 0;
    sh[threadIdx.x] = v;
    __syncthreads();
    for (int off = 1; off < 256; off <<= 1) {
        int add = (threadIdx.x >= off) ? sh[threadIdx.x - off] : 0;
        __syncthreads();
        sh[threadIdx.x] += add;
        __syncthreads();
    }
    if (i < NA) base[i] = sh[threadIdx.x] - v;     // exclusive
    if (threadIdx.x == 255) bsum[blockIdx.x] = sh[255];
}

__global__ void k_scan2(int* __restrict__ bsum, int nb) {
    if (threadIdx.x == 0 && blockIdx.x == 0) {
        int run = 0;
        for (int i = 0; i < nb; ++i) { int v = bsum[i]; bsum[i] = run; run += v; }
    }
}

__global__ void k_scan3(const int* __restrict__ bsum, int* __restrict__ base,
                        int* __restrict__ cursor) {
    int i = blockIdx.x * 256 + threadIdx.x;
    if (i < NA) {
        int b = base[i] + bsum[blockIdx.x];
        base[i]   = b;
        cursor[i] = b;
    }
}

__global__ void k_reorder(const int* __restrict__ pl, int* __restrict__ cursor,
                          int* __restrict__ perm) {
    int p = blockIdx.x * 256 + threadIdx.x;
    if (p < NP) {
        int pos = atomicAdd(&cursor[pl[p]], 1);
        perm[pos] = p;
    }
}

// ---------------------------------------------------------------------------
// K2-MFMA: fused filter network (bf16 MFMA, fp32 acc) + gather + sorted
// LDS-aggregated scatter. 64 sorted pairs / block, 4 waves.
//   wave w owns m-tile w (pairs 16w..16w+15).
//   phase1: C1[64x128] = F[64x32] @ Wf1  (1 k-step), ssp -> TmpB bf16 (LDS)
//   phase2: C2[64x128] = Tmp @ Wf2       (4 k-steps), kept in C-layout regs
//   phase3: v = (C2+bf2)*cut*h[j]; run-combine by slot -> SlotAcc (LDS);
//           flush one global-atomic row per distinct atom.
// ---------------------------------------------------------------------------
__global__ __launch_bounds__(256) void k_pairs_mfma(
        const int*   __restrict__ perm,
        const int*   __restrict__ pl,
        const float* __restrict__ fij,
        const float* __restrict__ fcut,
        const float* __restrict__ h,
        const short* __restrict__ Wf1T,
        const float* __restrict__ bf1,
        const short* __restrict__ Wf2T,
        const float* __restrict__ bf2,
        float* __restrict__ acc_out) {
    __shared__ float SlotAcc[64 * 132];              // 33792 B (phase3)
    unsigned short* TmpB = (unsigned short*)SlotAcc; // [64][136] bf16 (phase1/2 alias)
    __shared__ int   ajs[64], slots[64], slot_atom[64], sps_s[64];
    __shared__ float cuts[64];
    __shared__ int   nslots_s;

    const int t    = threadIdx.x;
    const int p0   = blockIdx.x * 64;
    const int lane = t & 63;
    const int wv   = t >> 6;          // wave id = m-tile
    const int q    = lane >> 4;       // quad
    const int ln   = lane & 15;

    if (t < 64) {   // exactly wave 0
        int sp = perm[p0 + t];
        int ai = pl[sp];
        sps_s[t] = sp;
        ajs[t]   = pl[NP + sp];
        cuts[t]  = fcut[sp];
        int prev = __shfl_up(ai, 1);
        bool head = (t == 0) || (ai != prev);
        unsigned long long mask = __ballot(head);
        int slot = __popcll(mask & ((2ULL << t) - 1)) - 1;
        slots[t] = slot;
        if (head) slot_atom[slot] = ai;
        if (t == 0) nslots_s = (int)__popcll(mask);
    }
    __syncthreads();

    // ---- phase 1: C1 = F @ Wf1 (A built in-reg from gathered f_ij rows) ----
    short8 aF;
    {
        const float* fr = fij + (size_t)sps_s[16 * wv + ln] * NRBF + q * 8;
        float4 f0 = *(const float4*)(fr);
        float4 f1 = *(const float4*)(fr + 4);
        aF = (short8){f2bf(f0.x), f2bf(f0.y), f2bf(f0.z), f2bf(f0.w),
                      f2bf(f1.x), f2bf(f1.y), f2bf(f1.z), f2bf(f1.w)};
    }
    f32x4 c1[8];
    #pragma unroll
    for (int tt = 0; tt < 8; ++tt) {
        short8 b = *(const short8*)(Wf1T + (16 * tt + ln) * NRBF + q * 8);
        f32x4 z = {0.f, 0.f, 0.f, 0.f};
        c1[tt] = __builtin_amdgcn_mfma_f32_16x16x32_bf16(aF, b, z, 0, 0, 0);
    }

    // ssp + bias, C-layout -> TmpB[pair][k] bf16 (A-layout for phase 2)
    #pragma unroll
    for (int tt = 0; tt < 8; ++tt) {
        float bias = bf1[16 * tt + ln];
        #pragma unroll
        for (int r = 0; r < 4; ++r) {
            float v = ssp_f(c1[tt][r] + bias);
            TmpB[(16 * wv + 4 * q + r) * 136 + 16 * tt + ln] = (unsigned short)f2bf(v);
        }
    }
    __syncthreads();

    // ---- phase 2: C2 = Tmp @ Wf2, 4 k-steps, B-frags from global bf16 ----
    f32x4 c2[8];
    #pragma unroll
    for (int tt = 0; tt < 8; ++tt) c2[tt] = (f32x4){0.f, 0.f, 0.f, 0.f};
    #pragma unroll
    for (int kk = 0; kk < 4; ++kk) {
        short8 a = *(const short8*)(TmpB + (16 * wv + ln) * 136 + kk * 32 + q * 8);
        #pragma unroll
        for (int tt = 0; tt < 8; ++tt) {
            short8 b = *(const short8*)(Wf2T + (size_t)(16 * tt + ln) * FDIM + kk * 32 + q * 8);
            c2[tt] = __builtin_amdgcn_mfma_f32_16x16x32_bf16(a, b, c2[tt], 0, 0, 0);
        }
    }
    __syncthreads();   // all TmpB reads done; SlotAcc may now overwrite

    for (int i = t; i < 64 * 132; i += 256) SlotAcc[i] = 0.f;
    __syncthreads();

    // ---- phase 3: consume C-layout directly (cols strided 16) ----
    float bf2v[8];
    #pragma unroll
    for (int tt = 0; tt < 8; ++tt) bf2v[tt] = bf2[16 * tt + ln];

    {
        float run[8] = {};
        const int base_p = 16 * wv + 4 * q;
        int cur = slots[base_p];
        #pragma unroll
        for (int r = 0; r < 4; ++r) {
            int p = base_p + r;
            int s = slots[p];
            if (s != cur) {
                #pragma unroll
                for (int tt = 0; tt < 8; ++tt) {
                    atomicAdd(&SlotAcc[cur * 132 + 16 * tt + ln], run[tt]);
                    run[tt] = 0.f;
                }
                cur = s;
            }
            float cut = cuts[p];
            const float* hr = h + (size_t)ajs[p] * FDIM;
            #pragma unroll
            for (int tt = 0; tt < 8; ++tt)
                run[tt] += (c2[tt][r] + bf2v[tt]) * cut * hr[16 * tt + ln];
        }
        #pragma unroll
        for (int tt = 0; tt < 8; ++tt)
            atomicAdd(&SlotAcc[cur * 132 + 16 * tt + ln], run[tt]);
    }
    __syncthreads();

    // ---- flush: one global-atomic row per distinct atom in this block ----
    const int nslots = nslots_s;
    const int c0 = (t & 15) * 8;
    for (int s = (t >> 4); s < nslots; s += 16) {
        float* outp = acc_out + (size_t)slot_atom[s] * FDIM + c0;
        #pragma unroll
        for (int j = 0; j < 8; ++j)
            unsafeAtomicAdd(outp + j, SlotAcc[s * 132 + c0 + j]);
    }
}

// ---------------------------------------------------------------------------
// K2-unsorted fallback if ws is too small.
// ---------------------------------------------------------------------------
__global__ __launch_bounds__(256) void k_pairs(const int*   __restrict__ pl,
                                               const float* __restrict__ fij,
                                               const float* __restrict__ fcut,
                                               const float* __restrict__ h,
                                               const float* __restrict__ Wf1,
                                               const float* __restrict__ bf1,
                                               const float* __restrict__ Wf2,
                                               const float* __restrict__ bf2,
                                               float* __restrict__ acc_out) {
    __shared__ float Fs[64 * 36];
    __shared__ float Tmp[64 * 132];
    __shared__ int   pis[64], pjs[64];
    __shared__ float cuts[64];

    const int t  = threadIdx.x;
    const int p0 = blockIdx.x * 64;

    const float4* fv = (const float4*)(fij + (size_t)p0 * NRBF);
    #pragma unroll
    for (int i = 0; i < 2; ++i) {
        int idx = t + i * 256;
        int row = idx >> 3;
        int c4  = idx & 7;
        *(float4*)(&Fs[row * 36 + c4 * 4]) = fv[idx];
    }
    if (t < 64) {
        pis[t]  = pl[p0 + t];
        pjs[t]  = pl[NP + p0 + t];
        cuts[t] = fcut[p0 + t];
    }
    __syncthreads();

    const int c0 = (t & 15) * 8;
    const int r0 = (t >> 4) * 4;

    float a1[4][8] = {};
    #pragma unroll 4
    for (int k = 0; k < NRBF; ++k) {
        float4 w0 = *(const float4*)(Wf1 + k * FDIM + c0);
        float4 w1 = *(const float4*)(Wf1 + k * FDIM + c0 + 4);
        float wv[8] = {w0.x, w0.y, w0.z, w0.w, w1.x, w1.y, w1.z, w1.w};
        float xr[4];
        #pragma unroll
        for (int i = 0; i < 4; ++i) xr[i] = Fs[(r0 + i) * 36 + k];
        #pragma unroll
        for (int i = 0; i < 4; ++i)
            #pragma unroll
            for (int j = 0; j < 8; ++j)
                a1[i][j] += xr[i] * wv[j];
    }
    {
        float4 b0 = *(const float4*)(bf1 + c0);
        float4 b1 = *(const float4*)(bf1 + c0 + 4);
        float bv[8] = {b0.x, b0.y, b0.z, b0.w, b1.x, b1.y, b1.z, b1.w};
        #pragma unroll
        for (int i = 0; i < 4; ++i)
            #pragma unroll
            for (int j = 0; j < 8; ++j)
                Tmp[(r0 + i) * 132 + c0 + j] = ssp_f(a1[i][j] + bv[j]);
    }
    __syncthreads();

    float a2[4][8] = {};
    #pragma unroll 2
    for (int k = 0; k < FDIM; ++k) {
        float4 w0 = *(const float4*)(Wf2 + k * FDIM + c0);
        float4 w1 = *(const float4*)(Wf2 + k * FDIM + c0 + 4);
        float wv[8] = {w0.x, w0.y, w0.z, w0.w, w1.x, w1.y, w1.z, w1.w};
        float xr[4];
        #pragma unroll
        for (int i = 0; i < 4; ++i) xr[i] = Tmp[(r0 + i) * 132 + k];
        #pragma unroll
        for (int i = 0; i < 4; ++i)
            #pragma unroll
            for (int j = 0; j < 8; ++j)
                a2[i][j] += xr[i] * wv[j];
    }

    float4 b20 = *(const float4*)(bf2 + c0);
    float4 b21 = *(const float4*)(bf2 + c0 + 4);
    float bv[8] = {b20.x, b20.y, b20.z, b20.w, b21.x, b21.y, b21.z, b21.w};
    #pragma unroll
    for (int i = 0; i < 4; ++i) {
        int   p   = r0 + i;
        float cut = cuts[p];
        const float* hr = h + (size_t)pjs[p] * FDIM + c0;
        float4 h0 = *(const float4*)(hr);
        float4 h1 = *(const float4*)(hr + 4);
        float hv[8] = {h0.x, h0.y, h0.z, h0.w, h1.x, h1.y, h1.z, h1.w};
        float* outp = acc_out + (size_t)pis[p] * FDIM + c0;
        #pragma unroll
        for (int j = 0; j < 8; ++j)
            unsafeAtomicAdd(outp + j, (a2[i][j] + bv[j]) * cut * hv[j]);
    }
}

// ---------------------------------------------------------------------------
// K3: out = ssp(acc @ Wo1 + bo1) @ Wo2 + bo2. 32 atoms per 256-thread block.
// ---------------------------------------------------------------------------
__global__ __launch_bounds__(256) void k_out(const float* __restrict__ acc_in,
                                             const float* __restrict__ Wo1,
                                             const float* __restrict__ bo1,
                                             const float* __restrict__ Wo2,
                                             const float* __restrict__ bo2,
                                             float* __restrict__ out) {
    __shared__ float As[32 * 132];
    __shared__ float O1[32 * 132];
    const int t   = threadIdx.x;
    const int r0g = blockIdx.x * 32;

    const float4* av = (const float4*)(acc_in + (size_t)r0g * FDIM);
    #pragma unroll
    for (int i = 0; i < 4; ++i) {
        int idx = t + i * 256;
        int row = idx >> 5;
        int c4  = idx & 31;
        *(float4*)(&As[row * 132 + c4 * 4]) = av[idx];
    }
    __syncthreads();

    const int c0 = (t & 15) * 8;
    const int r0 = (t >> 4) * 2;

    float acc[2][8] = {};
    #pragma unroll 4
    for (int k = 0; k < FDIM; ++k) {
        float xa = As[r0 * 132 + k];
        float xb = As[(r0 + 1) * 132 + k];
        float4 w0 = *(const float4*)(Wo1 + k * FDIM + c0);
        float4 w1 = *(const float4*)(Wo1 + k * FDIM + c0 + 4);
        float wv[8] = {w0.x, w0.y, w0.z, w0.w, w1.x, w1.y, w1.z, w1.w};
        #pragma unroll
        for (int j = 0; j < 8; ++j) {
            acc[0][j] += xa * wv[j];
            acc[1][j] += xb * wv[j];
        }
    }
    {
        float4 b0 = *(const float4*)(bo1 + c0);
        float4 b1 = *(const float4*)(bo1 + c0 + 4);
        float bv[8] = {b0.x, b0.y, b0.z, b0.w, b1.x, b1.y, b1.z, b1.w};
        #pragma unroll
        for (int i = 0; i < 2; ++i)
            #pragma unroll
            for (int j = 0; j < 8; ++j)
                O1[(r0 + i) * 132 + c0 + j] = ssp_f(acc[i][j] + bv[j]);
    }
    __syncthreads();

    float acc2[2][8] = {};
    #pragma unroll 4
    for (int k = 0; k < FDIM; ++k) {
        float xa = O1[r0 * 132 + k];
        float xb = O1[(r0 + 1) * 132 + k];
        float4 w0 = *(const float4*)(Wo2 + k * FDIM + c0);
        float4 w1 = *(const float4*)(Wo2 + k * FDIM + c0 + 4);
        float wv[8] = {w0.x, w0.y, w0.z, w0.w, w1.x, w1.y, w1.z, w1.w};
        #pragma unroll
        for (int j = 0; j < 8; ++j) {
            acc2[0][j] += xa * wv[j];
            acc2[1][j] += xb * wv[j];
        }
    }
    float4 b0 = *(const float4*)(bo2 + c0);
    float4 b1 = *(const float4*)(bo2 + c0 + 4);
    float bv[8] = {b0.x, b0.y, b0.z, b0.w, b1.x, b1.y, b1.z, b1.w};
    #pragma unroll
    for (int i = 0; i < 2; ++i) {
        float4 o0 = {acc2[i][0] + bv[0], acc2[i][1] + bv[1],
                     acc2[i][2] + bv[2], acc2[i][3] + bv[3]};
        float4 o1 = {acc2[i][4] + bv[4], acc2[i][5] + bv[5],
                     acc2[i][6] + bv[6], acc2[i][7] + bv[7]};
        float* op = out + (size_t)(r0g + r0 + i) * FDIM + c0;
        *(float4*)(op)     = o0;
        *(float4*)(op + 4) = o1;
    }
}

extern "C" void kernel_launch(void* const* d_in, const int* in_sizes, int n_in,
                              void* d_out, int out_size, void* d_ws, size_t ws_size,
                              hipStream_t stream) {
    const float* x    = (const float*)d_in[0];
    const int*   pl   = (const int*)  d_in[1];
    const float* fij  = (const float*)d_in[2];
    const float* fcut = (const float*)d_in[3];
    const float* W_in = (const float*)d_in[4];
    const float* Wf1  = (const float*)d_in[5];
    const float* bf1  = (const float*)d_in[6];
    const float* Wf2  = (const float*)d_in[7];
    const float* bf2  = (const float*)d_in[8];
    const float* Wo1  = (const float*)d_in[9];
    const float* bo1  = (const float*)d_in[10];
    const float* Wo2  = (const float*)d_in[11];
    const float* bo2  = (const float*)d_in[12];
    float* out = (float*)d_out;

    // ws layout
    char*  wsp   = (char*)d_ws;
    float* h     = (float*)wsp;                              // NA*128 f32
    float* acc   = h + (size_t)NA * FDIM;                    // NA*128 f32
    int*   count = (int*)(acc + (size_t)NA * FDIM);          // NA int
    int*   base  = count + NA;                               // NA int
    int*   cursor= base + NA;                                // NA int
    int*   bsum  = cursor + NA;                              // 512 int
    int*   perm  = bsum + 512;                               // NP int
    short* Wf1T  = (short*)(perm + NP);                      // 128*32 bf16
    short* Wf2T  = Wf1T + 128 * 32;                          // 128*128 bf16

    const size_t needed = (size_t)NA * FDIM * 2 * 4
                        + ((size_t)NA * 3 + 512 + NP) * 4
                        + (size_t)(128 * 32 + 128 * 128) * 2;
    const bool sorted_path = (ws_size >= needed);

    const int NB = (NA + 255) / 256;   // 391 scan blocks

    hipMemsetAsync(acc, 0, (size_t)NA * FDIM * sizeof(float), stream);
    k_in_proj<<<NA / 32, 256, 0, stream>>>(x, W_in, h);

    if (sorted_path) {
        k_prep   <<<64, 256, 0, stream>>>(Wf1, Wf2, Wf1T, Wf2T);
        hipMemsetAsync(count, 0, (size_t)NA * sizeof(int), stream);
        k_hist   <<<(NP + 255) / 256, 256, 0, stream>>>(pl, count);
        k_scan1  <<<NB, 256, 0, stream>>>(count, base, bsum);
        k_scan2  <<<1, 64, 0, stream>>>(bsum, NB);
        k_scan3  <<<NB, 256, 0, stream>>>(bsum, base, cursor);
        k_reorder<<<(NP + 255) / 256, 256, 0, stream>>>(pl, cursor, perm);
        k_pairs_mfma<<<NP / 64, 256, 0, stream>>>(perm, pl, fij, fcut, h,
                                                  Wf1T, bf1, Wf2T, bf2, acc);
    } else {
        k_pairs<<<NP / 64, 256, 0, stream>>>(pl, fij, fcut, h,
                                             Wf1, bf1, Wf2, bf2, acc);
    }

    k_out<<<NA / 32, 256, 0, stream>>>(acc, Wo1, bo1, Wo2, bo2, out);
}

// Round 4
// 1365.494 us; speedup vs baseline: 4.6687x; 1.2237x over previous
//
#include <hip/hip_runtime.h>

#define NA   100000
#define NP   1600000
#define FDIM 128
#define NRBF 32
#define LN2  0.69314718055994530942f

typedef __attribute__((ext_vector_type(8))) short short8;  // 8 bf16 = 4 VGPRs
typedef __attribute__((ext_vector_type(4))) float f32x4;

// ShiftedSoftplus via hardware exp2/log2:
// softplus(x)-ln2 = max(x,0) + ln2*(log2(1 + 2^(-|x|*log2e)) - 1)
__device__ __forceinline__ float ssp_f(float v) {
    float e = __builtin_amdgcn_exp2f(fabsf(v) * -1.4426950408889634f);
    float l = __builtin_amdgcn_logf(1.0f + e);          // log2
    return fmaxf(v, 0.0f) + 0.6931471805599453f * (l - 1.0f);
}

// f32 -> bf16 with round-to-nearest-even
__device__ __forceinline__ short f2bf(float f) {
    union { float f; unsigned u; } v; v.f = f;
    unsigned r = v.u + 0x7FFF + ((v.u >> 16) & 1);
    return (short)(r >> 16);
}

// ---------------------------------------------------------------------------
// K0: pre-transpose all weights to bf16 [n][k] in ws.
// ---------------------------------------------------------------------------
__global__ void k_prep(const float* __restrict__ Wf1, const float* __restrict__ Wf2,
                       const float* __restrict__ Wo1, const float* __restrict__ Wo2,
                       const float* __restrict__ Win,
                       short* __restrict__ Wf1T, short* __restrict__ Wf2T,
                       short* __restrict__ Wo1T, short* __restrict__ Wo2T,
                       short* __restrict__ WinT) {
    int i = blockIdx.x * 256 + threadIdx.x;          // 64 blocks -> 16384
    int n = i >> 7, k = i & 127;
    Wf2T[i] = f2bf(Wf2[k * FDIM + n]);
    Wo1T[i] = f2bf(Wo1[k * FDIM + n]);
    Wo2T[i] = f2bf(Wo2[k * FDIM + n]);
    WinT[i] = f2bf(Win[k * FDIM + n]);
    if (i < 128 * 32) {
        int n1 = i >> 5, k1 = i & 31;
        Wf1T[i] = f2bf(Wf1[k1 * FDIM + n1]);
    }
}

// ---------------------------------------------------------------------------
// K1-MFMA: h = x @ W_in (no bias). 64 atoms / 256-thread block, 4 waves.
// ---------------------------------------------------------------------------
__global__ __launch_bounds__(256) void k_in_proj_mfma(
        const float* __restrict__ x, const short* __restrict__ WinT,
        float* __restrict__ h) {
    __shared__ __attribute__((aligned(16))) char lds[64 * 132 * 4]; // 33792 B
    unsigned short* XsB = (unsigned short*)lds;        // [64][136] bf16
    float* Of = (float*)lds;                           // [64][132] f32 (alias)

    const int t = threadIdx.x;
    const int r0g = blockIdx.x * 64;
    const int lane = t & 63, wv = t >> 6, q = lane >> 4, ln = lane & 15;

    // stage x tile -> bf16 LDS (row layout)
    #pragma unroll
    for (int i = 0; i < 4; ++i) {
        int idx = i * 256 + t;
        int row = idx >> 4, ch = idx & 15;             // 16 chunks of 8 floats
        float4 a = {0,0,0,0}, b = {0,0,0,0};
        if (r0g + row < NA) {
            const float* xp = x + (size_t)(r0g + row) * FDIM + ch * 8;
            a = *(const float4*)xp;
            b = *(const float4*)(xp + 4);
        }
        short8 s = {f2bf(a.x), f2bf(a.y), f2bf(a.z), f2bf(a.w),
                    f2bf(b.x), f2bf(b.y), f2bf(b.z), f2bf(b.w)};
        *(short8*)(XsB + row * 136 + ch * 8) = s;
    }
    __syncthreads();

    f32x4 c[8];
    #pragma unroll
    for (int tt = 0; tt < 8; ++tt) c[tt] = (f32x4){0.f, 0.f, 0.f, 0.f};
    #pragma unroll
    for (int kk = 0; kk < 4; ++kk) {
        short8 a = *(const short8*)(XsB + (16 * wv + ln) * 136 + kk * 32 + q * 8);
        #pragma unroll
        for (int tt = 0; tt < 8; ++tt) {
            short8 b = *(const short8*)(WinT + (16 * tt + ln) * FDIM + kk * 32 + q * 8);
            c[tt] = __builtin_amdgcn_mfma_f32_16x16x32_bf16(a, b, c[tt], 0, 0, 0);
        }
    }
    __syncthreads();   // XsB reads done; Of may overwrite

    #pragma unroll
    for (int tt = 0; tt < 8; ++tt)
        #pragma unroll
        for (int r = 0; r < 4; ++r)
            Of[(16 * wv + 4 * q + r) * 132 + 16 * tt + ln] = c[tt][r];
    __syncthreads();

    #pragma unroll
    for (int i = 0; i < 8; ++i) {
        int idx = i * 256 + t;
        int row = idx >> 5, ch = idx & 31;             // 32 float4 per row
        if (r0g + row < NA)
            *(float4*)(h + (size_t)(r0g + row) * FDIM + ch * 4) =
                *(const float4*)(Of + row * 132 + ch * 4);
    }
}

// ---------------------------------------------------------------------------
// Sort pipeline: counting sort of pairs by idx_i.
// ---------------------------------------------------------------------------
__global__ void k_hist(const int* __restrict__ pl, int* __restrict__ count) {
    int p = blockIdx.x * 256 + threadIdx.x;
    if (p < NP) atomicAdd(&count[pl[p]], 1);
}

__global__ __launch_bounds__(256) void k_scan1(const int* __restrict__ count,
                                               int* __restrict__ base,
                                               int* __restrict__ bsum) {
    __shared__ int sh[256];
    int i = blockIdx.x * 256 + threadIdx.x;
    int v = (i < NA) ? count[i] : 0;
    sh[threadIdx.x] = v;
    __syncthreads();
    for (int off = 1; off < 256; off <<= 1) {
        int add = (threadIdx.x >= off) ? sh[threadIdx.x - off] : 0;
        __syncthreads();
        sh[threadIdx.x] += add;
        __syncthreads();
    }
    if (i < NA) base[i] = sh[threadIdx.x] - v;     // exclusive
    if (threadIdx.x == 255) bsum[blockIdx.x] = sh[255];
}

// parallel single-block scan of block sums (nb <= 512)
__global__ __launch_bounds__(512) void k_scan2(int* __restrict__ bsum, int nb) {
    __shared__ int sh[512];
    int t = threadIdx.x;
    int v = (t < nb) ? bsum[t] : 0;
    sh[t] = v;
    __syncthreads();
    for (int off = 1; off < 512; off <<= 1) {
        int add = (t >= off) ? sh[t - off] : 0;
        __syncthreads();
        sh[t] += add;
        __syncthreads();
    }
    if (t < nb) bsum[t] = sh[t] - v;               // exclusive
}

__global__ void k_scan3(const int* __restrict__ bsum, int* __restrict__ base,
                        int* __restrict__ cursor) {
    int i = blockIdx.x * 256 + threadIdx.x;
    if (i < NA) {
        int b = base[i] + bsum[blockIdx.x];
        base[i]   = b;
        cursor[i] = b;
    }
}

__global__ void k_reorder(const int* __restrict__ pl, int* __restrict__ cursor,
                          int* __restrict__ perm) {
    int p = blockIdx.x * 256 + threadIdx.x;
    if (p < NP) {
        int pos = atomicAdd(&cursor[pl[p]], 1);
        perm[pos] = p;
    }
}

// ---------------------------------------------------------------------------
// K2-MFMA: fused filter network (bf16 MFMA) + gather + sorted LDS scatter.
// ---------------------------------------------------------------------------
__global__ __launch_bounds__(256) void k_pairs_mfma(
        const int*   __restrict__ perm,
        const int*   __restrict__ pl,
        const float* __restrict__ fij,
        const float* __restrict__ fcut,
        const float* __restrict__ h,
        const short* __restrict__ Wf1T,
        const float* __restrict__ bf1,
        const short* __restrict__ Wf2T,
        const float* __restrict__ bf2,
        float* __restrict__ acc_out) {
    __shared__ float SlotAcc[64 * 132];              // 33792 B (phase3)
    unsigned short* TmpB = (unsigned short*)SlotAcc; // [64][136] bf16 (alias)
    __shared__ int   ajs[64], slots[64], slot_atom[64], sps_s[64];
    __shared__ float cuts[64];
    __shared__ int   nslots_s;

    const int t    = threadIdx.x;
    const int p0   = blockIdx.x * 64;
    const int lane = t & 63;
    const int wv   = t >> 6;          // wave id = m-tile
    const int q    = lane >> 4;       // quad
    const int ln   = lane & 15;

    if (t < 64) {   // exactly wave 0
        int sp = perm[p0 + t];
        int ai = pl[sp];
        sps_s[t] = sp;
        ajs[t]   = pl[NP + sp];
        cuts[t]  = fcut[sp];
        int prev = __shfl_up(ai, 1);
        bool head = (t == 0) || (ai != prev);
        unsigned long long mask = __ballot(head);
        int slot = __popcll(mask & ((2ULL << t) - 1)) - 1;
        slots[t] = slot;
        if (head) slot_atom[slot] = ai;
        if (t == 0) nslots_s = (int)__popcll(mask);
    }
    __syncthreads();

    // ---- phase 1: C1 = F @ Wf1 (A built in-reg from gathered f_ij rows) ----
    short8 aF;
    {
        const float* fr = fij + (size_t)sps_s[16 * wv + ln] * NRBF + q * 8;
        float4 f0 = *(const float4*)(fr);
        float4 f1 = *(const float4*)(fr + 4);
        aF = (short8){f2bf(f0.x), f2bf(f0.y), f2bf(f0.z), f2bf(f0.w),
                      f2bf(f1.x), f2bf(f1.y), f2bf(f1.z), f2bf(f1.w)};
    }
    f32x4 c1[8];
    #pragma unroll
    for (int tt = 0; tt < 8; ++tt) {
        short8 b = *(const short8*)(Wf1T + (16 * tt + ln) * NRBF + q * 8);
        f32x4 z = {0.f, 0.f, 0.f, 0.f};
        c1[tt] = __builtin_amdgcn_mfma_f32_16x16x32_bf16(aF, b, z, 0, 0, 0);
    }

    // ssp + bias, C-layout -> TmpB[pair][k] bf16 (A-layout for phase 2)
    #pragma unroll
    for (int tt = 0; tt < 8; ++tt) {
        float bias = bf1[16 * tt + ln];
        #pragma unroll
        for (int r = 0; r < 4; ++r) {
            float v = ssp_f(c1[tt][r] + bias);
            TmpB[(16 * wv + 4 * q + r) * 136 + 16 * tt + ln] = (unsigned short)f2bf(v);
        }
    }
    __syncthreads();

    // ---- phase 2: C2 = Tmp @ Wf2, 4 k-steps ----
    f32x4 c2[8];
    #pragma unroll
    for (int tt = 0; tt < 8; ++tt) c2[tt] = (f32x4){0.f, 0.f, 0.f, 0.f};
    #pragma unroll
    for (int kk = 0; kk < 4; ++kk) {
        short8 a = *(const short8*)(TmpB + (16 * wv + ln) * 136 + kk * 32 + q * 8);
        #pragma unroll
        for (int tt = 0; tt < 8; ++tt) {
            short8 b = *(const short8*)(Wf2T + (size_t)(16 * tt + ln) * FDIM + kk * 32 + q * 8);
            c2[tt] = __builtin_amdgcn_mfma_f32_16x16x32_bf16(a, b, c2[tt], 0, 0, 0);
        }
    }
    __syncthreads();   // all TmpB reads done; SlotAcc may now overwrite

    for (int i = t; i < 64 * 132; i += 256) SlotAcc[i] = 0.f;
    __syncthreads();

    // ---- phase 3: consume C-layout directly (cols strided 16) ----
    float bf2v[8];
    #pragma unroll
    for (int tt = 0; tt < 8; ++tt) bf2v[tt] = bf2[16 * tt + ln];

    {
        float run[8] = {};
        const int base_p = 16 * wv + 4 * q;
        int cur = slots[base_p];
        #pragma unroll
        for (int r = 0; r < 4; ++r) {
            int p = base_p + r;
            int s = slots[p];
            if (s != cur) {
                #pragma unroll
                for (int tt = 0; tt < 8; ++tt) {
                    atomicAdd(&SlotAcc[cur * 132 + 16 * tt + ln], run[tt]);
                    run[tt] = 0.f;
                }
                cur = s;
            }
            float cut = cuts[p];
            const float* hr = h + (size_t)ajs[p] * FDIM;
            #pragma unroll
            for (int tt = 0; tt < 8; ++tt)
                run[tt] += (c2[tt][r] + bf2v[tt]) * cut * hr[16 * tt + ln];
        }
        #pragma unroll
        for (int tt = 0; tt < 8; ++tt)
            atomicAdd(&SlotAcc[cur * 132 + 16 * tt + ln], run[tt]);
    }
    __syncthreads();

    // ---- flush: one global-atomic row per distinct atom in this block ----
    const int nslots = nslots_s;
    const int c0 = (t & 15) * 8;
    for (int s = (t >> 4); s < nslots; s += 16) {
        float* outp = acc_out + (size_t)slot_atom[s] * FDIM + c0;
        #pragma unroll
        for (int j = 0; j < 8; ++j)
            unsafeAtomicAdd(outp + j, SlotAcc[s * 132 + c0 + j]);
    }
}

// ---------------------------------------------------------------------------
// K3-MFMA: out = ssp(acc @ Wo1 + bo1) @ Wo2 + bo2. 64 atoms / block.
// ---------------------------------------------------------------------------
__global__ __launch_bounds__(256) void k_out_mfma(
        const float* __restrict__ acc_in,
        const short* __restrict__ Wo1T, const float* __restrict__ bo1,
        const short* __restrict__ Wo2T, const float* __restrict__ bo2,
        float* __restrict__ out) {
    __shared__ __attribute__((aligned(16))) char lds[64 * 136 * 2 * 2]; // 34816 B
    unsigned short* AsB = (unsigned short*)lds;                  // [64][136]
    unsigned short* O1B = (unsigned short*)(lds + 64 * 136 * 2); // [64][136]
    float* Of = (float*)lds;                                     // [64][132] alias

    const int t = threadIdx.x;
    const int r0g = blockIdx.x * 64;
    const int lane = t & 63, wv = t >> 6, q = lane >> 4, ln = lane & 15;

    // stage acc -> bf16 LDS
    #pragma unroll
    for (int i = 0; i < 4; ++i) {
        int idx = i * 256 + t;
        int row = idx >> 4, ch = idx & 15;
        float4 a = {0,0,0,0}, b = {0,0,0,0};
        if (r0g + row < NA) {
            const float* ap = acc_in + (size_t)(r0g + row) * FDIM + ch * 8;
            a = *(const float4*)ap;
            b = *(const float4*)(ap + 4);
        }
        short8 s = {f2bf(a.x), f2bf(a.y), f2bf(a.z), f2bf(a.w),
                    f2bf(b.x), f2bf(b.y), f2bf(b.z), f2bf(b.w)};
        *(short8*)(AsB + row * 136 + ch * 8) = s;
    }
    __syncthreads();

    // GEMM1: C1 = A @ Wo1T ; ssp(+bo1) -> bf16 O1B
    f32x4 c1[8];
    #pragma unroll
    for (int tt = 0; tt < 8; ++tt) c1[tt] = (f32x4){0.f, 0.f, 0.f, 0.f};
    #pragma unroll
    for (int kk = 0; kk < 4; ++kk) {
        short8 a = *(const short8*)(AsB + (16 * wv + ln) * 136 + kk * 32 + q * 8);
        #pragma unroll
        for (int tt = 0; tt < 8; ++tt) {
            short8 b = *(const short8*)(Wo1T + (16 * tt + ln) * FDIM + kk * 32 + q * 8);
            c1[tt] = __builtin_amdgcn_mfma_f32_16x16x32_bf16(a, b, c1[tt], 0, 0, 0);
        }
    }
    #pragma unroll
    for (int tt = 0; tt < 8; ++tt) {
        float bias = bo1[16 * tt + ln];
        #pragma unroll
        for (int r = 0; r < 4; ++r) {
            float v = ssp_f(c1[tt][r] + bias);
            O1B[(16 * wv + 4 * q + r) * 136 + 16 * tt + ln] = (unsigned short)f2bf(v);
        }
    }
    __syncthreads();

    // GEMM2: C2 = O1 @ Wo2T + bo2
    f32x4 c2[8];
    #pragma unroll
    for (int tt = 0; tt < 8; ++tt) c2[tt] = (f32x4){0.f, 0.f, 0.f, 0.f};
    #pragma unroll
    for (int kk = 0; kk < 4; ++kk) {
        short8 a = *(const short8*)(O1B + (16 * wv + ln) * 136 + kk * 32 + q * 8);
        #pragma unroll
        for (int tt = 0; tt < 8; ++tt) {
            short8 b = *(const short8*)(Wo2T + (16 * tt + ln) * FDIM + kk * 32 + q * 8);
            c2[tt] = __builtin_amdgcn_mfma_f32_16x16x32_bf16(a, b, c2[tt], 0, 0, 0);
        }
    }
    __syncthreads();   // all O1B reads done; Of overwrites lds

    #pragma unroll
    for (int tt = 0; tt < 8; ++tt) {
        float bias = bo2[16 * tt + ln];
        #pragma unroll
        for (int r = 0; r < 4; ++r)
            Of[(16 * wv + 4 * q + r) * 132 + 16 * tt + ln] = c2[tt][r] + bias;
    }
    __syncthreads();

    #pragma unroll
    for (int i = 0; i < 8; ++i) {
        int idx = i * 256 + t;
        int row = idx >> 5, ch = idx & 31;
        if (r0g + row < NA)
            *(float4*)(out + (size_t)(r0g + row) * FDIM + ch * 4) =
                *(const float4*)(Of + row * 132 + ch * 4);
    }
}

// ---------------------------------------------------------------------------
// fp32 fallback kernels (ws too small for sort+transpose buffers)
// ---------------------------------------------------------------------------
__global__ __launch_bounds__(256) void k_in_proj(const float* __restrict__ x,
                                                 const float* __restrict__ W,
                                                 float* __restrict__ h) {
    __shared__ float Xs[32 * 132];
    const int t  = threadIdx.x;
    const int r0g = blockIdx.x * 32;
    const float4* xv = (const float4*)(x + (size_t)r0g * FDIM);
    #pragma unroll
    for (int i = 0; i < 4; ++i) {
        int idx = t + i * 256;
        *(float4*)(&Xs[(idx >> 5) * 132 + (idx & 31) * 4]) = xv[idx];
    }
    __syncthreads();
    const int c0 = (t & 15) * 8;
    const int r0 = (t >> 4) * 2;
    float acc[2][8] = {};
    #pragma unroll 4
    for (int k = 0; k < FDIM; ++k) {
        float xa = Xs[r0 * 132 + k];
        float xb = Xs[(r0 + 1) * 132 + k];
        float4 w0 = *(const float4*)(W + k * FDIM + c0);
        float4 w1 = *(const float4*)(W + k * FDIM + c0 + 4);
        float wv[8] = {w0.x, w0.y, w0.z, w0.w, w1.x, w1.y, w1.z, w1.w};
        #pragma unroll
        for (int j = 0; j < 8; ++j) {
            acc[0][j] += xa * wv[j];
            acc[1][j] += xb * wv[j];
        }
    }
    #pragma unroll
    for (int i = 0; i < 2; ++i) {
        float4 o0 = {acc[i][0], acc[i][1], acc[i][2], acc[i][3]};
        float4 o1 = {acc[i][4], acc[i][5], acc[i][6], acc[i][7]};
        float* hp = h + (size_t)(r0g + r0 + i) * FDIM + c0;
        *(float4*)(hp) = o0;  *(float4*)(hp + 4) = o1;
    }
}

__global__ __launch_bounds__(256) void k_pairs(const int*   __restrict__ pl,
                                               const float* __restrict__ fij,
                                               const float* __restrict__ fcut,
                                               const float* __restrict__ h,
                                               const float* __restrict__ Wf1,
                                               const float* __restrict__ bf1,
                                               const float* __restrict__ Wf2,
                                               const float* __restrict__ bf2,
                                               float* __restrict__ acc_out) {
    __shared__ float Fs[64 * 36];
    __shared__ float Tmp[64 * 132];
    __shared__ int   pis[64], pjs[64];
    __shared__ float cuts[64];
    const int t  = threadIdx.x;
    const int p0 = blockIdx.x * 64;
    const float4* fv = (const float4*)(fij + (size_t)p0 * NRBF);
    #pragma unroll
    for (int i = 0; i < 2; ++i) {
        int idx = t + i * 256;
        *(float4*)(&Fs[(idx >> 3) * 36 + (idx & 7) * 4]) = fv[idx];
    }
    if (t < 64) {
        pis[t]  = pl[p0 + t];
        pjs[t]  = pl[NP + p0 + t];
        cuts[t] = fcut[p0 + t];
    }
    __syncthreads();
    const int c0 = (t & 15) * 8;
    const int r0 = (t >> 4) * 4;
    float a1[4][8] = {};
    #pragma unroll 4
    for (int k = 0; k < NRBF; ++k) {
        float4 w0 = *(const float4*)(Wf1 + k * FDIM + c0);
        float4 w1 = *(const float4*)(Wf1 + k * FDIM + c0 + 4);
        float wv[8] = {w0.x, w0.y, w0.z, w0.w, w1.x, w1.y, w1.z, w1.w};
        float xr[4];
        #pragma unroll
        for (int i = 0; i < 4; ++i) xr[i] = Fs[(r0 + i) * 36 + k];
        #pragma unroll
        for (int i = 0; i < 4; ++i)
            #pragma unroll
            for (int j = 0; j < 8; ++j)
                a1[i][j] += xr[i] * wv[j];
    }
    {
        float4 b0 = *(const float4*)(bf1 + c0);
        float4 b1 = *(const float4*)(bf1 + c0 + 4);
        float bv[8] = {b0.x, b0.y, b0.z, b0.w, b1.x, b1.y, b1.z, b1.w};
        #pragma unroll
        for (int i = 0; i < 4; ++i)
            #pragma unroll
            for (int j = 0; j < 8; ++j)
                Tmp[(r0 + i) * 132 + c0 + j] = ssp_f(a1[i][j] + bv[j]);
    }
    __syncthreads();
    float a2[4][8] = {};
    #pragma unroll 2
    for (int k = 0; k < FDIM; ++k) {
        float4 w0 = *(const float4*)(Wf2 + k * FDIM + c0);
        float4 w1 = *(const float4*)(Wf2 + k * FDIM + c0 + 4);
        float wv[8] = {w0.x, w0.y, w0.z, w0.w, w1.x, w1.y, w1.z, w1.w};
        float xr[4];
        #pragma unroll
        for (int i = 0; i < 4; ++i) xr[i] = Tmp[(r0 + i) * 132 + k];
        #pragma unroll
        for (int i = 0; i < 4; ++i)
            #pragma unroll
            for (int j = 0; j < 8; ++j)
                a2[i][j] += xr[i] * wv[j];
    }
    float4 b20 = *(const float4*)(bf2 + c0);
    float4 b21 = *(const float4*)(bf2 + c0 + 4);
    float bv[8] = {b20.x, b20.y, b20.z, b20.w, b21.x, b21.y, b21.z, b21.w};
    #pragma unroll
    for (int i = 0; i < 4; ++i) {
        int   p   = r0 + i;
        float cut = cuts[p];
        const float* hr = h + (size_t)pjs[p] * FDIM + c0;
        float4 h0 = *(const float4*)(hr);
        float4 h1 = *(const float4*)(hr + 4);
        float hv[8] = {h0.x, h0.y, h0.z, h0.w, h1.x, h1.y, h1.z, h1.w};
        float* outp = acc_out + (size_t)pis[p] * FDIM + c0;
        #pragma unroll
        for (int j = 0; j < 8; ++j)
            unsafeAtomicAdd(outp + j, (a2[i][j] + bv[j]) * cut * hv[j]);
    }
}

__global__ __launch_bounds__(256) void k_out(const float* __restrict__ acc_in,
                                             const float* __restrict__ Wo1,
                                             const float* __restrict__ bo1,
                                             const float* __restrict__ Wo2,
                                             const float* __restrict__ bo2,
                                             float* __restrict__ out) {
    __shared__ float As[32 * 132];
    __shared__ float O1[32 * 132];
    const int t   = threadIdx.x;
    const int r0g = blockIdx.x * 32;
    const float4* av = (const float4*)(acc_in + (size_t)r0g * FDIM);
    #pragma unroll
    for (int i = 0; i < 4; ++i) {
        int idx = t + i * 256;
        *(float4*)(&As[(idx >> 5) * 132 + (idx & 31) * 4]) = av[idx];
    }
    __syncthreads();
    const int c0 = (t & 15) * 8;
    const int r0 = (t >> 4) * 2;
    float acc[2][8] = {};
    #pragma unroll 4
    for (int k = 0; k < FDIM; ++k) {
        float xa = As[r0 * 132 + k];
        float xb = As[(r0 + 1) * 132 + k];
        float4 w0 = *(const float4*)(Wo1 + k * FDIM + c0);
        float4 w1 = *(const float4*)(Wo1 + k * FDIM + c0 + 4);
        float wv[8] = {w0.x, w0.y, w0.z, w0.w, w1.x, w1.y, w1.z, w1.w};
        #pragma unroll
        for (int j = 0; j < 8; ++j) {
            acc[0][j] += xa * wv[j];
            acc[1][j] += xb * wv[j];
        }
    }
    {
        float4 b0 = *(const float4*)(bo1 + c0);
        float4 b1 = *(const float4*)(bo1 + c0 + 4);
        float bv[8] = {b0.x, b0.y, b0.z, b0.w, b1.x, b1.y, b1.z, b1.w};
        #pragma unroll
        for (int i = 0; i < 2; ++i)
            #pragma unroll
            for (int j = 0; j < 8; ++j)
                O1[(r0 + i) * 132 + c0 + j] = ssp_f(acc[i][j] + bv[j]);
    }
    __syncthreads();
    float acc2[2][8] = {};
    #pragma unroll 4
    for (int k = 0; k < FDIM; ++k) {
        float xa = O1[r0 * 132 + k];
        float xb = O1[(r0 + 1) * 132 + k];
        float4 w0 = *(const float4*)(Wo2 + k * FDIM + c0);
        float4 w1 = *(const float4*)(Wo2 + k * FDIM + c0 + 4);
        float wv[8] = {w0.x, w0.y, w0.z, w0.w, w1.x, w1.y, w1.z, w1.w};
        #pragma unroll
        for (int j = 0; j < 8; ++j) {
            acc2[0][j] += xa * wv[j];
            acc2[1][j] += xb * wv[j];
        }
    }
    float4 b0 = *(const float4*)(bo2 + c0);
    float4 b1 = *(const float4*)(bo2 + c0 + 4);
    float bv[8] = {b0.x, b0.y, b0.z, b0.w, b1.x, b1.y, b1.z, b1.w};
    #pragma unroll
    for (int i = 0; i < 2; ++i) {
        float4 o0 = {acc2[i][0] + bv[0], acc2[i][1] + bv[1],
                     acc2[i][2] + bv[2], acc2[i][3] + bv[3]};
        float4 o1 = {acc2[i][4] + bv[4], acc2[i][5] + bv[5],
                     acc2[i][6] + bv[6], acc2[i][7] + bv[7]};
        float* op = out + (size_t)(r0g + r0 + i) * FDIM + c0;
        *(float4*)(op) = o0;  *(float4*)(op + 4) = o1;
    }
}

extern "C" void kernel_launch(void* const* d_in, const int* in_sizes, int n_in,
                              void* d_out, int out_size, void* d_ws, size_t ws_size,
                              hipStream_t stream) {
    const float* x    = (const float*)d_in[0];
    const int*   pl   = (const int*)  d_in[1];
    const float* fij  = (const float*)d_in[2];
    const float* fcut = (const float*)d_in[3];
    const float* W_in = (const float*)d_in[4];
    const float* Wf1  = (const float*)d_in[5];
    const float* bf1  = (const float*)d_in[6];
    const float* Wf2  = (const float*)d_in[7];
    const float* bf2  = (const float*)d_in[8];
    const float* Wo1  = (const float*)d_in[9];
    const float* bo1  = (const float*)d_in[10];
    const float* Wo2  = (const float*)d_in[11];
    const float* bo2  = (const float*)d_in[12];
    float* out = (float*)d_out;

    // ws layout
    char*  wsp   = (char*)d_ws;
    float* h     = (float*)wsp;                              // NA*128 f32
    float* acc   = h + (size_t)NA * FDIM;                    // NA*128 f32
    int*   count = (int*)(acc + (size_t)NA * FDIM);          // NA int
    int*   base  = count + NA;                               // NA int
    int*   cursor= base + NA;                                // NA int
    int*   bsum  = cursor + NA;                              // 512 int
    int*   perm  = bsum + 512;                               // NP int
    short* Wf1T  = (short*)(perm + NP);                      // 128*32 bf16
    short* Wf2T  = Wf1T + 128 * 32;                          // 128*128 bf16
    short* Wo1T  = Wf2T + 128 * 128;
    short* Wo2T  = Wo1T + 128 * 128;
    short* WinT  = Wo2T + 128 * 128;

    const size_t needed = (size_t)NA * FDIM * 2 * 4
                        + ((size_t)NA * 3 + 512 + NP) * 4
                        + (size_t)(128 * 32 + 4 * 128 * 128) * 2;
    const bool sorted_path = (ws_size >= needed);

    const int NB  = (NA + 255) / 256;   // 391 scan blocks
    const int NBA = (NA + 63) / 64;     // 1563 atom-tile blocks

    hipMemsetAsync(acc, 0, (size_t)NA * FDIM * sizeof(float), stream);

    if (sorted_path) {
        k_prep   <<<64, 256, 0, stream>>>(Wf1, Wf2, Wo1, Wo2, W_in,
                                          Wf1T, Wf2T, Wo1T, Wo2T, WinT);
        hipMemsetAsync(count, 0, (size_t)NA * sizeof(int), stream);
        k_in_proj_mfma<<<NBA, 256, 0, stream>>>(x, WinT, h);
        k_hist   <<<(NP + 255) / 256, 256, 0, stream>>>(pl, count);
        k_scan1  <<<NB, 256, 0, stream>>>(count, base, bsum);
        k_scan2  <<<1, 512, 0, stream>>>(bsum, NB);
        k_scan3  <<<NB, 256, 0, stream>>>(bsum, base, cursor);
        k_reorder<<<(NP + 255) / 256, 256, 0, stream>>>(pl, cursor, perm);
        k_pairs_mfma<<<NP / 64, 256, 0, stream>>>(perm, pl, fij, fcut, h,
                                                  Wf1T, bf1, Wf2T, bf2, acc);
        k_out_mfma<<<NBA, 256, 0, stream>>>(acc, Wo1T, bo1, Wo2T, bo2, out);
    } else {
        k_in_proj<<<NA / 32, 256, 0, stream>>>(x, W_in, h);
        k_pairs<<<NP / 64, 256, 0, stream>>>(pl, fij, fcut, h,
                                             Wf1, bf1, Wf2, bf2, acc);
        k_out<<<NA / 32, 256, 0, stream>>>(acc, Wo1, bo1, Wo2, bo2, out);
    }
}